// Round 6
// baseline (931.157 us; speedup 1.0000x reference)
//
#include <hip/hip_runtime.h>
#include <math.h>

#define D_MODEL  2048
#define D_INNER  2048
#define N_QK     32
#define N_V      32
#define D_STATE  64
#define D_CONV   4
#define CHUNK    128
#define CONV_DIM 6144      // D_INNER + 2*N_QK*D_STATE
#define IN_OUT   8224      // 2*D_INNER + 2*N_QK*D_STATE + N_V
#define BATCH    2
#define SEQ      4096
#define M_ROWS   (BATCH*SEQ)   // 8192
#define NCHUNK   (SEQ/CHUNK)   // 32

typedef unsigned short bf16_t;
typedef __attribute__((ext_vector_type(4))) float f32x4;
typedef __attribute__((ext_vector_type(8))) short bf16x8;

// swizzled row-major LDS index (elem units); XOR bits 3-5 spread rows over banks
#define SWZ64(r,c)  ((((r)*64)  + (c)) ^ (((r)&7)<<3))
#define SWZ128(r,c) ((((r)*128) + (c)) ^ (((r)&7)<<3))

__device__ __forceinline__ float b2f(bf16_t u) {
    union { unsigned int i; float f; } w; w.i = ((unsigned int)u) << 16; return w.f;
}
__device__ __forceinline__ bf16_t f2b(float f) {
    unsigned int x = __float_as_uint(f);
    return (bf16_t)((x + 0x7FFFu + ((x >> 16) & 1u)) >> 16);   // RNE
}
__device__ __forceinline__ void store4b(bf16_t* dst, float4 v) {
    ushort4 u; u.x = f2b(v.x); u.y = f2b(v.y); u.z = f2b(v.z); u.w = f2b(v.w);
    *reinterpret_cast<ushort4*>(dst) = u;
}

__device__ __forceinline__ void gload_lds16(const bf16_t* g, bf16_t* l) {
    __builtin_amdgcn_global_load_lds((const __attribute__((address_space(1))) void*)g,
                                     (__attribute__((address_space(3))) void*)l,
                                     16, 0, 0);
}

// ---------------------------------------------------------------------------
// fp32 -> bf16 convert
// ---------------------------------------------------------------------------
__global__ __launch_bounds__(256) void f2b_kernel(const float* __restrict__ in,
                                                  bf16_t* __restrict__ out, long n)
{
    const long i = ((long)blockIdx.x * 256 + threadIdx.x) * 4;
    if (i < n) {
        float4 v = *reinterpret_cast<const float4*>(in + i);
        ushort4 o;
        o.x = f2b(v.x); o.y = f2b(v.y); o.z = f2b(v.z); o.w = f2b(v.w);
        *reinterpret_cast<ushort4*>(out + i) = o;
    }
}

// ---------------------------------------------------------------------------
// 256x256 bf16 MFMA NT-GEMM, depth-4 counted-vmcnt pipeline (T2+T3+T4+T5).
// BK=32, 4 LDS buffers (128 KiB), stage t+3 while computing t, wait vmcnt(8)
// (never 0 in steady state). 512 thr = 8 waves (2Mx4N); per-wave 128x64 out.
// LDS layout per operand: [pair(=2 rows)][8 x 16B chunks], chunk ^= pair&7.
// Requires M%256==0, NTB*256 valid B rows, K%32==0, grid%8==0.
// ---------------------------------------------------------------------------
template<int NTB, int K, bool OBF16>
__global__ __launch_bounds__(512, 2) void gemm256(const bf16_t* __restrict__ A,
                                                  const bf16_t* __restrict__ B,
                                                  void* __restrict__ Cv,
                                                  long ldc)
{
    constexpr int BK = 32;
    constexpr int NT = K / BK;
    __shared__ bf16_t As[4][128 * 64];   // 16 KiB per buffer
    __shared__ bf16_t Bs[4][128 * 64];

    const int nwg = gridDim.x;
    const int bid = blockIdx.x;
    const int wg  = ((nwg & 7) == 0) ? ((bid & 7) * (nwg >> 3) + (bid >> 3)) : bid;
    const int bm = (wg / NTB) * 256;
    const int bn = (wg % NTB) * 256;

    const int tid  = threadIdx.x;
    const int lane = tid & 63;
    const int wv   = tid >> 6;
    const int wr   = wv >> 2, wc = wv & 3;       // 2x4 wave grid
    const int l15  = lane & 15, l4 = lane >> 4;  // l4 = k-chunk 0..3

    f32x4 acc[8][4];
    #pragma unroll
    for (int i = 0; i < 8; ++i)
        #pragma unroll
        for (int j = 0; j < 4; ++j) acc[i][j] = (f32x4){0.f, 0.f, 0.f, 0.f};

    const bf16_t* Abase = A + (long)bm * K;
    const bf16_t* Bbase = B + (long)bn * K;

    // stage K-tile t into buffer buf: linear LDS slot s=(pair,c16) holds the
    // global element for logical chunk lc = c16 ^ (pair&7): row=2*pair+(lc>>2),
    // k-chunk = lc&3. Involution => read side uses the same XOR.
    auto stage = [&](int t, int buf) {
        const bf16_t* Ab = Abase + t * BK;
        const bf16_t* Bb = Bbase + t * BK;
        #pragma unroll
        for (int it = 0; it < 2; ++it) {
            const int s = it * 512 + tid;           // slot 0..1023
            const int pair = s >> 3, c16 = s & 7;
            const int lc  = c16 ^ (pair & 7);
            const int row = 2 * pair + (lc >> 2);
            const long go = (long)row * K + (lc & 3) * 8;
            gload_lds16(Ab + go, &As[buf][s * 8]);
            gload_lds16(Bb + go, &Bs[buf][s * 8]);
        }
    };
    auto rdA = [&](int buf, int r) {
        const int pair = r >> 1;
        const int lc = ((r & 1) << 2) | l4;
        return *reinterpret_cast<const bf16x8*>(&As[buf][pair * 64 + ((lc ^ (pair & 7)) << 3)]);
    };
    auto rdB = [&](int buf, int r) {
        const int pair = r >> 1;
        const int lc = ((r & 1) << 2) | l4;
        return *reinterpret_cast<const bf16x8*>(&Bs[buf][pair * 64 + ((lc ^ (pair & 7)) << 3)]);
    };

    stage(0, 0); stage(1, 1); stage(2, 2);          // 12 loads in flight
    asm volatile("s_waitcnt vmcnt(8)" ::: "memory");  // tile 0 landed
    __builtin_amdgcn_s_barrier();

    for (int t = 0; t < NT; ++t) {
        const int buf = t & 3;
        if (t + 3 < NT) stage(t + 3, (t + 3) & 3);  // buffer freed at iter t-1
        bf16x8 bfr[4], af[4];
        #pragma unroll
        for (int ni = 0; ni < 4; ++ni) bfr[ni] = rdB(buf, wc * 64 + ni * 16 + l15);
        #pragma unroll
        for (int mi = 0; mi < 4; ++mi) af[mi] = rdA(buf, wr * 128 + mi * 16 + l15);
        __builtin_amdgcn_s_setprio(1);
        #pragma unroll
        for (int mi = 0; mi < 4; ++mi)
            #pragma unroll
            for (int ni = 0; ni < 4; ++ni)
                acc[mi][ni] = __builtin_amdgcn_mfma_f32_16x16x32_bf16(
                    af[mi], bfr[ni], acc[mi][ni], 0, 0, 0);
        __builtin_amdgcn_s_setprio(0);
        __builtin_amdgcn_s_barrier();               // phase cohesion
        #pragma unroll
        for (int mi = 0; mi < 4; ++mi) af[mi] = rdA(buf, wr * 128 + 64 + mi * 16 + l15);
        __builtin_amdgcn_s_setprio(1);
        #pragma unroll
        for (int mi = 0; mi < 4; ++mi)
            #pragma unroll
            for (int ni = 0; ni < 4; ++ni)
                acc[4 + mi][ni] = __builtin_amdgcn_mfma_f32_16x16x32_bf16(
                    af[mi], bfr[ni], acc[4 + mi][ni], 0, 0, 0);
        __builtin_amdgcn_s_setprio(0);
        // counted wait: tile t+1 landed, t+2/t+3 stay in flight (T4)
        if (t < NT - 3)       { asm volatile("s_waitcnt vmcnt(8)" ::: "memory"); }
        else if (t == NT - 3) { asm volatile("s_waitcnt vmcnt(4)" ::: "memory"); }
        else if (t == NT - 2) { asm volatile("s_waitcnt vmcnt(0)" ::: "memory"); }
        __builtin_amdgcn_s_barrier();
    }

    #pragma unroll
    for (int mf = 0; mf < 8; ++mf) {
        const long grow0 = bm + wr * 128 + mf * 16 + l4 * 4;   // mf*16 == qm*64+mi*16
        #pragma unroll
        for (int ni = 0; ni < 4; ++ni) {
            const int gcol = bn + wc * 64 + ni * 16 + l15;
            #pragma unroll
            for (int j = 0; j < 4; ++j) {
                if (OBF16)
                    ((bf16_t*)Cv)[(grow0 + j) * ldc + gcol] = f2b(acc[mf][ni][j]);
                else
                    ((float*)Cv)[(grow0 + j) * ldc + gcol] = acc[mf][ni][j];
            }
        }
    }
}

// ---------------------------------------------------------------------------
// 128x128 m97-style MFMA GEMM (kept for the 32-col A_log tail), ldc-param.
// ---------------------------------------------------------------------------
template<int N, int K, bool OBF16>
__global__ __launch_bounds__(256) void gemm_mfma(const bf16_t* __restrict__ A,
                                                 const bf16_t* __restrict__ B,
                                                 void* __restrict__ Cv,
                                                 long ldc)
{
    constexpr int BM = 128, BN = 128, BK = 64;
    constexpr int NTB = (N + BN - 1) / BN;
    __shared__ bf16_t As[BM * BK];
    __shared__ bf16_t Bs[BM * BK];

    const int nwg = gridDim.x;
    const int bid = blockIdx.x;
    const int wg  = ((nwg & 7) == 0) ? ((bid & 7) * (nwg >> 3) + (bid >> 3)) : bid;
    const int bm = (wg / NTB) * BM;
    const int bn = (wg % NTB) * BN;

    const int tid  = threadIdx.x;
    const int lane = tid & 63;
    const int wv   = tid >> 6;
    const int wr   = wv >> 1, wc = wv & 1;

    f32x4 acc[4][4];
    #pragma unroll
    for (int i = 0; i < 4; ++i)
        #pragma unroll
        for (int j = 0; j < 4; ++j) acc[i][j] = (f32x4){0.f, 0.f, 0.f, 0.f};

    for (int k0 = 0; k0 < K; k0 += BK) {
        #pragma unroll
        for (int it = 0; it < 4; ++it) {
            const int seg = it * 256 + tid;
            const int row = seg >> 3, c16 = seg & 7;
            gload_lds16(A + (long)(bm + row) * K + k0 + c16 * 8,
                        &As[row * BK + c16 * 8]);
            int brow = bn + row;
            if constexpr (N % BN != 0) brow = min(brow, N - 1);
            gload_lds16(B + (long)brow * K + k0 + c16 * 8,
                        &Bs[row * BK + c16 * 8]);
        }
        __syncthreads();
        #pragma unroll
        for (int kk = 0; kk < 2; ++kk) {
            bf16x8 af[4], bfr[4];
            const int kc = kk * 32 + (lane >> 4) * 8;
            #pragma unroll
            for (int mi = 0; mi < 4; ++mi) {
                const int row = wr * 64 + mi * 16 + (lane & 15);
                af[mi] = *reinterpret_cast<const bf16x8*>(&As[row * BK + kc]);
            }
            #pragma unroll
            for (int ni = 0; ni < 4; ++ni) {
                const int row = wc * 64 + ni * 16 + (lane & 15);
                bfr[ni] = *reinterpret_cast<const bf16x8*>(&Bs[row * BK + kc]);
            }
            #pragma unroll
            for (int mi = 0; mi < 4; ++mi)
                #pragma unroll
                for (int ni = 0; ni < 4; ++ni)
                    acc[mi][ni] = __builtin_amdgcn_mfma_f32_16x16x32_bf16(
                        af[mi], bfr[ni], acc[mi][ni], 0, 0, 0);
        }
        __syncthreads();
    }

    #pragma unroll
    for (int mi = 0; mi < 4; ++mi) {
        const long row0 = bm + wr * 64 + mi * 16 + ((lane >> 4) << 2);
        #pragma unroll
        for (int ni = 0; ni < 4; ++ni) {
            const int col = bn + wc * 64 + ni * 16 + (lane & 15);
            if (N % BN != 0 && col >= N) continue;
            #pragma unroll
            for (int j = 0; j < 4; ++j) {
                if (OBF16)
                    ((bf16_t*)Cv)[(row0 + j) * ldc + col] = f2b(acc[mi][ni][j]);
                else
                    ((float*)Cv)[(row0 + j) * ldc + col] = acc[mi][ni][j];
            }
        }
    }
}

// ---------------------------------------------------------------------------
// Fused causal depthwise conv (K=4), 4 consecutive columns, reading bf16 xBCzA.
// ---------------------------------------------------------------------------
__device__ __forceinline__ float4 conv4v(const bf16_t* __restrict__ xb, long m, int l,
                                         int col, const float* __restrict__ cw,
                                         const float* __restrict__ cbv)
{
    float4 acc = *reinterpret_cast<const float4*>(cbv + col);
    float4 wc0 = *reinterpret_cast<const float4*>(cw + (long)col * 4);
    float4 wc1 = *reinterpret_cast<const float4*>(cw + (long)col * 4 + 4);
    float4 wc2 = *reinterpret_cast<const float4*>(cw + (long)col * 4 + 8);
    float4 wc3 = *reinterpret_cast<const float4*>(cw + (long)col * 4 + 12);
    const float t0[4] = {wc0.x, wc0.y, wc0.z, wc0.w};
    const float t1[4] = {wc1.x, wc1.y, wc1.z, wc1.w};
    const float t2[4] = {wc2.x, wc2.y, wc2.z, wc2.w};
    const float t3[4] = {wc3.x, wc3.y, wc3.z, wc3.w};
    #pragma unroll
    for (int tap = 0; tap < 4; ++tap) {
        if (l - 3 + tap < 0) continue;
        const bf16_t* p = xb + (m - 3 + tap) * (long)IN_OUT + col;
        ushort4 v = *reinterpret_cast<const ushort4*>(p);
        acc.x = fmaf(b2f(v.x), t0[tap], acc.x);
        acc.y = fmaf(b2f(v.y), t1[tap], acc.y);
        acc.z = fmaf(b2f(v.z), t2[tap], acc.z);
        acc.w = fmaf(b2f(v.w), t3[tap], acc.w);
    }
    return acc;
}

// dt = softplus(A_log)
__global__ __launch_bounds__(256) void dt_kernel(const bf16_t* __restrict__ xb,
                                                 float* __restrict__ dt)
{
    const int i = blockIdx.x * 256 + threadIdx.x;
    if (i < M_ROWS * N_V) {
        const int m = i >> 5, h = i & 31;
        const float a = b2f(xb[(long)m * IN_OUT + (CONV_DIM + D_INNER) + h]);
        dt[i] = (a > 20.f) ? a : log1pf(expf(a));
    }
}

// ---------------------------------------------------------------------------
// Phase A: per (b, chunk, head) -> in-chunk cumsum(-dt), chunk states, decay.
// ---------------------------------------------------------------------------
__global__ __launch_bounds__(256) void ssd_states(const bf16_t* __restrict__ xb,
                                                  const float* __restrict__ dt,
                                                  const float* __restrict__ cw,
                                                  const float* __restrict__ cbv,
                                                  float* __restrict__ states,
                                                  float* __restrict__ cumbuf,
                                                  float* __restrict__ cdecay)
{
    const int h = blockIdx.x, c = blockIdx.y, b = blockIdx.z;
    __shared__ float sB[CHUNK][68];
    __shared__ float sx[CHUNK][68];
    __shared__ float cum[CHUNK];
    const int t = threadIdx.x;
    const long mbase = (long)b * SEQ + (long)c * CHUNK;
    if (t < CHUNK) cum[t] = -dt[(mbase + t) * N_V + h];
    for (int idx = t; idx < CHUNK * 16; idx += 256) {
        const int k = idx >> 4, q4 = (idx & 15) * 4;
        const long m = mbase + k;
        const int l = (int)(m & (SEQ - 1));
        float4 xv = conv4v(xb, m, l, h * 64 + q4, cw, cbv);
        float4 bv = conv4v(xb, m, l, D_INNER + h * 64 + q4, cw, cbv);
        *reinterpret_cast<float4*>(&sx[k][q4]) = xv;
        *reinterpret_cast<float4*>(&sB[k][q4]) = bv;
    }
    __syncthreads();
    if (t == 0) { float s = 0.f; for (int k = 0; k < CHUNK; ++k) { s += cum[k]; cum[k] = s; } }
    __syncthreads();
    const float clast = cum[CHUNK - 1];
    const int p = t >> 2, n0 = (t & 3) * 16;
    float acc[16];
    #pragma unroll
    for (int j = 0; j < 16; ++j) acc[j] = 0.f;
    for (int k = 0; k < CHUNK; ++k) {
        const float sxk = sx[k][p] * __expf(clast - cum[k]);
        #pragma unroll
        for (int j = 0; j < 16; ++j) acc[j] = fmaf(sB[k][n0 + j], sxk, acc[j]);
    }
    const long cb = ((long)b * NCHUNK + c) * N_QK + h;
    const long sbase = (cb * 64 + p) * 64 + n0;
    #pragma unroll
    for (int j = 0; j < 16; ++j) states[sbase + j] = acc[j];
    if (t < CHUNK) cumbuf[cb * CHUNK + t] = cum[t];
    if (t == 0)   cdecay[cb] = __expf(clast);
}

// ---------------------------------------------------------------------------
// Phase B: sequential inter-chunk scan, 64 blocks (b*h).
// ---------------------------------------------------------------------------
__global__ __launch_bounds__(256) void ssd_scan(float* __restrict__ states,
                                                const float* __restrict__ cdecay)
{
    const int bh = blockIdx.x;
    const int b = bh >> 5, h = bh & 31;
    const int t = threadIdx.x;
    float carry[16];
    #pragma unroll
    for (int j = 0; j < 16; ++j) carry[j] = 0.f;
    for (int c = 0; c < NCHUNK; ++c) {
        const long cb = ((long)b * NCHUNK + c) * N_QK + h;
        const long base = cb * 4096 + (long)t * 16;
        const float cd = cdecay[cb];
        #pragma unroll
        for (int v = 0; v < 4; ++v) {
            float4 st = *reinterpret_cast<const float4*>(&states[base + v * 4]);
            float4 pv = make_float4(carry[v*4], carry[v*4+1], carry[v*4+2], carry[v*4+3]);
            *reinterpret_cast<float4*>(&states[base + v * 4]) = pv;
            carry[v*4]   = fmaf(carry[v*4],   cd, st.x);
            carry[v*4+1] = fmaf(carry[v*4+1], cd, st.y);
            carry[v*4+2] = fmaf(carry[v*4+2], cd, st.z);
            carry[v*4+3] = fmaf(carry[v*4+3], cd, st.w);
        }
    }
}

// ---------------------------------------------------------------------------
// Phase C (MFMA): S=C·B^T (tri+decay) -> Q bf16 -> y = Q·x + e·(C·prev^T) + D·x
// gate silu(z+zb) -> yz bf16. 4 waves, wave-private Q, no inner barriers.
// ---------------------------------------------------------------------------
__global__ __launch_bounds__(256) void ssd_out(const bf16_t* __restrict__ xb,
                                               const float* __restrict__ cumbuf,
                                               const float* __restrict__ prevst,
                                               const float* __restrict__ Dvec,
                                               const float* __restrict__ zbias,
                                               const float* __restrict__ cw,
                                               const float* __restrict__ cbv,
                                               bf16_t* __restrict__ yz)
{
    const int h = blockIdx.x, c = blockIdx.y, b = blockIdx.z;
    __shared__ bf16_t sC[128 * 64];
    __shared__ bf16_t sB[128 * 64];
    __shared__ bf16_t sXQ[128 * 64];   // x tile, later aliased as Q
    __shared__ bf16_t sXT[64 * 128];   // x^T
    __shared__ bf16_t sP[64 * 64];     // prev state (bf16)
    __shared__ float  cum[CHUNK];
    const int t = threadIdx.x;
    const long mbase = (long)b * SEQ + (long)c * CHUNK;
    const long cb = ((long)b * NCHUNK + c) * N_QK + h;
    if (t < CHUNK) cum[t] = cumbuf[cb * CHUNK + t];
    for (int idx = t; idx < CHUNK * 16; idx += 256) {
        const int k = idx >> 4, q4 = (idx & 15) * 4;
        const long m = mbase + k;
        const int l = (int)(m & (SEQ - 1));
        float4 xv = conv4v(xb, m, l, h * 64 + q4, cw, cbv);
        float4 bv = conv4v(xb, m, l, D_INNER + h * 64 + q4, cw, cbv);
        float4 cv = conv4v(xb, m, l, 2 * D_INNER + h * 64 + q4, cw, cbv);
        store4b(&sXQ[SWZ64(k, q4)], xv);
        store4b(&sB [SWZ64(k, q4)], bv);
        store4b(&sC [SWZ64(k, q4)], cv);
    }
    for (int idx = t; idx < 64 * 16; idx += 256) {
        const int p = idx >> 4, q4 = (idx & 15) * 4;
        float4 v = *reinterpret_cast<const float4*>(prevst + cb * 4096 + p * 64 + q4);
        store4b(&sP[SWZ64(p, q4)], v);
    }
    __syncthreads();
    {
        const int j = t & 127;
        const int c8b = (t >> 7) * 4;
        #pragma unroll
        for (int it = 0; it < 4; ++it) {
            const int c8 = c8b + it;
            bf16x8 v = *reinterpret_cast<const bf16x8*>(&sXQ[SWZ64(j, c8 * 8)]);
            #pragma unroll
            for (int e = 0; e < 8; ++e) sXT[SWZ128(c8 * 8 + e, j)] = v[e];
        }
    }
    __syncthreads();   // sXQ now dead as x; becomes wave-private Q

    const int lane = t & 63, wv = t >> 6;
    const int w32 = wv * 32, l15 = lane & 15, l4 = lane >> 4;
    bf16_t* sQ = sXQ;

    f32x4 yac[2][4], iac[2][4];
    #pragma unroll
    for (int mi = 0; mi < 2; ++mi)
        #pragma unroll
        for (int np = 0; np < 4; ++np) {
            yac[mi][np] = (f32x4){0.f, 0.f, 0.f, 0.f};
            iac[mi][np] = (f32x4){0.f, 0.f, 0.f, 0.f};
        }

    #pragma unroll
    for (int H = 0; H < 2; ++H) {
        if (H == 1 && wv < 2) break;
        const int j0 = H * 64;
        f32x4 sac[2][4];
        #pragma unroll
        for (int mi = 0; mi < 2; ++mi)
            #pragma unroll
            for (int nj = 0; nj < 4; ++nj) sac[mi][nj] = (f32x4){0.f, 0.f, 0.f, 0.f};
        #pragma unroll
        for (int kk = 0; kk < 2; ++kk) {
            const int kc = kk * 32 + l4 * 8;
            bf16x8 af0 = *reinterpret_cast<const bf16x8*>(&sC[SWZ64(w32 + l15, kc)]);
            bf16x8 af1 = *reinterpret_cast<const bf16x8*>(&sC[SWZ64(w32 + 16 + l15, kc)]);
            #pragma unroll
            for (int nj = 0; nj < 4; ++nj) {
                bf16x8 bfj = *reinterpret_cast<const bf16x8*>(&sB[SWZ64(j0 + nj * 16 + l15, kc)]);
                if (j0 + nj * 16 <= w32 + 15)
                    sac[0][nj] = __builtin_amdgcn_mfma_f32_16x16x32_bf16(af0, bfj, sac[0][nj], 0, 0, 0);
                if (j0 + nj * 16 <= w32 + 31)
                    sac[1][nj] = __builtin_amdgcn_mfma_f32_16x16x32_bf16(af1, bfj, sac[1][nj], 0, 0, 0);
            }
        }
        #pragma unroll
        for (int mi = 0; mi < 2; ++mi) {
            #pragma unroll
            for (int nj = 0; nj < 4; ++nj) {
                const int jcol = nj * 16 + l15;
                const int jg = j0 + jcol;
                #pragma unroll
                for (int jj = 0; jj < 4; ++jj) {
                    const int i = w32 + mi * 16 + l4 * 4 + jj;
                    const float q = (jg <= i) ? __expf(cum[i] - cum[jg]) * sac[mi][nj][jj] : 0.f;
                    sQ[SWZ64(i, jcol)] = f2b(q);
                }
            }
        }
        #pragma unroll
        for (int kk = 0; kk < 2; ++kk) {
            const int kc = kk * 32 + l4 * 8;
            bf16x8 qa0 = *reinterpret_cast<const bf16x8*>(&sQ[SWZ64(w32 + l15, kc)]);
            bf16x8 qa1 = *reinterpret_cast<const bf16x8*>(&sQ[SWZ64(w32 + 16 + l15, kc)]);
            #pragma unroll
            for (int np = 0; np < 4; ++np) {
                bf16x8 xf = *reinterpret_cast<const bf16x8*>(&sXT[SWZ128(np * 16 + l15, j0 + kc)]);
                yac[0][np] = __builtin_amdgcn_mfma_f32_16x16x32_bf16(qa0, xf, yac[0][np], 0, 0, 0);
                yac[1][np] = __builtin_amdgcn_mfma_f32_16x16x32_bf16(qa1, xf, yac[1][np], 0, 0, 0);
            }
        }
    }
    #pragma unroll
    for (int kk = 0; kk < 2; ++kk) {
        const int kc = kk * 32 + l4 * 8;
        bf16x8 cf0 = *reinterpret_cast<const bf16x8*>(&sC[SWZ64(w32 + l15, kc)]);
        bf16x8 cf1 = *reinterpret_cast<const bf16x8*>(&sC[SWZ64(w32 + 16 + l15, kc)]);
        #pragma unroll
        for (int np = 0; np < 4; ++np) {
            bf16x8 pf = *reinterpret_cast<const bf16x8*>(&sP[SWZ64(np * 16 + l15, kc)]);
            iac[0][np] = __builtin_amdgcn_mfma_f32_16x16x32_bf16(cf0, pf, iac[0][np], 0, 0, 0);
            iac[1][np] = __builtin_amdgcn_mfma_f32_16x16x32_bf16(cf1, pf, iac[1][np], 0, 0, 0);
        }
    }
    const float dh = Dvec[h];
    #pragma unroll
    for (int mi = 0; mi < 2; ++mi) {
        #pragma unroll
        for (int jj = 0; jj < 4; ++jj) {
            const int i = w32 + mi * 16 + l4 * 4 + jj;
            const float ei = __expf(cum[i]);
            const long m = mbase + i;
            const bf16_t* zr = xb + m * (long)IN_OUT + CONV_DIM + h * 64;
            bf16_t* orow = yz + m * (long)D_INNER + h * 64;
            #pragma unroll
            for (int np = 0; np < 4; ++np) {
                const int p = np * 16 + l15;
                const float xval = b2f(sXT[SWZ128(p, i)]);
                const float y = yac[mi][np][jj] + ei * iac[mi][np][jj] + dh * xval;
                const float zv = b2f(zr[p]) + zbias[h * 64 + p];
                const float s = zv / (1.f + __expf(-zv));
                orow[p] = f2b(y * s);
            }
        }
    }
}

// ---------------------------------------------------------------------------
extern "C" void kernel_launch(void* const* d_in, const int* in_sizes, int n_in,
                              void* d_out, int out_size, void* d_ws, size_t ws_size,
                              hipStream_t stream)
{
    const float* u      = (const float*)d_in[0];
    const float* W_in   = (const float*)d_in[1];
    const float* conv_w = (const float*)d_in[2];
    const float* conv_b = (const float*)d_in[3];
    const float* Dv     = (const float*)d_in[4];
    const float* z_bias = (const float*)d_in[5];
    const float* W_out  = (const float*)d_in[6];
    float* out = (float*)d_out;

    char* w = (char*)d_ws;
    bf16_t* xbcza = (bf16_t*)w;  w += (long)M_ROWS * IN_OUT * 2;   // 128.5 MiB
    bf16_t* wob   = (bf16_t*)w;  w += (long)2048 * 2048 * 2;       //   8 MiB
    char* ureg = w;                                                 // ~66 MiB union
    bf16_t* ub  = (bf16_t*)ureg;                                    // 32 MiB (phase 1)
    bf16_t* wib = (bf16_t*)(ureg + (long)M_ROWS * D_MODEL * 2);     // 32.125 MiB (phase 1)
    bf16_t* yzb = (bf16_t*)ureg;                                    // 32 MiB (phase 2)
    float*  dtb = (float*)(ureg + (long)M_ROWS * D_INNER * 2);      //  1 MiB
    float*  cumb   = dtb + (long)M_ROWS * N_V;                      //  1 MiB
    float*  states = cumb + (long)BATCH * NCHUNK * N_QK * CHUNK;    // 32 MiB
    float*  cdec   = states + (long)BATCH * NCHUNK * N_QK * 4096;   //  8 KiB

    f2b_kernel<<<(int)(((long)M_ROWS * D_MODEL / 4 + 255) / 256), 256, 0, stream>>>(
        u, ub, (long)M_ROWS * D_MODEL);
    f2b_kernel<<<(int)(((long)IN_OUT * D_MODEL / 4 + 255) / 256), 256, 0, stream>>>(
        W_in, wib, (long)IN_OUT * D_MODEL);
    f2b_kernel<<<(int)(((long)D_MODEL * D_INNER / 4 + 255) / 256), 256, 0, stream>>>(
        W_out, wob, (long)D_MODEL * D_INNER);

    // GEMM1 main: cols [0, 8192) via 256^2 pipelined kernel (32x32 = 1024 wgs)
    gemm256<32, D_MODEL, true><<<(M_ROWS / 256) * 32, 512, 0, stream>>>(
        ub, wib, xbcza, IN_OUT);
    // GEMM1 tail: cols [8192, 8224) (A_log), 128^2 kernel, ldc = IN_OUT
    gemm_mfma<32, D_MODEL, true><<<(M_ROWS / 128), 256, 0, stream>>>(
        ub, wib + (long)8192 * D_MODEL, xbcza + 8192, IN_OUT);

    dt_kernel<<<(M_ROWS * N_V + 255) / 256, 256, 0, stream>>>(xbcza, dtb);

    ssd_states<<<dim3(N_QK, NCHUNK, BATCH), 256, 0, stream>>>(xbcza, dtb, conv_w, conv_b,
                                                              states, cumb, cdec);

    ssd_scan<<<BATCH * N_QK, 256, 0, stream>>>(states, cdec);

    ssd_out<<<dim3(N_QK, NCHUNK, BATCH), 256, 0, stream>>>(xbcza, cumb, states, Dv, z_bias,
                                                           conv_w, conv_b, yzb);

    // GEMM2: out = yz @ W_out^T  (8192 x 2048 x 2048), 32x8 = 256 wgs
    gemm256<8, D_INNER, false><<<(M_ROWS / 256) * 8, 512, 0, stream>>>(
        yzb, wob, out, D_MODEL);
}

// Round 7
// 837.942 us; speedup vs baseline: 1.1112x; 1.1112x over previous
//
#include <hip/hip_runtime.h>
#include <math.h>

#define D_MODEL  2048
#define D_INNER  2048
#define N_QK     32
#define N_V      32
#define D_STATE  64
#define D_CONV   4
#define CHUNK    128
#define CONV_DIM 6144      // D_INNER + 2*N_QK*D_STATE
#define IN_OUT   8224      // 2*D_INNER + 2*N_QK*D_STATE + N_V
#define BATCH    2
#define SEQ      4096
#define M_ROWS   (BATCH*SEQ)   // 8192
#define NCHUNK   (SEQ/CHUNK)   // 32

typedef unsigned short bf16_t;
typedef __attribute__((ext_vector_type(4))) float f32x4;
typedef __attribute__((ext_vector_type(8))) short bf16x8;

// swizzled row-major LDS index (elem units); XOR bits 3-5 spread rows over banks
#define SWZ64(r,c)  ((((r)*64)  + (c)) ^ (((r)&7)<<3))
#define SWZ128(r,c) ((((r)*128) + (c)) ^ (((r)&7)<<3))

__device__ __forceinline__ float b2f(bf16_t u) {
    union { unsigned int i; float f; } w; w.i = ((unsigned int)u) << 16; return w.f;
}
__device__ __forceinline__ bf16_t f2b(float f) {
    unsigned int x = __float_as_uint(f);
    return (bf16_t)((x + 0x7FFFu + ((x >> 16) & 1u)) >> 16);   // RNE
}
__device__ __forceinline__ void store4b(bf16_t* dst, float4 v) {
    ushort4 u; u.x = f2b(v.x); u.y = f2b(v.y); u.z = f2b(v.z); u.w = f2b(v.w);
    *reinterpret_cast<ushort4*>(dst) = u;
}

__device__ __forceinline__ void gload_lds16(const bf16_t* g, bf16_t* l) {
    __builtin_amdgcn_global_load_lds((const __attribute__((address_space(1))) void*)g,
                                     (__attribute__((address_space(3))) void*)l,
                                     16, 0, 0);
}

// ---------------------------------------------------------------------------
// fp32 -> bf16 convert
// ---------------------------------------------------------------------------
__global__ __launch_bounds__(256) void f2b_kernel(const float* __restrict__ in,
                                                  bf16_t* __restrict__ out, long n)
{
    const long i = ((long)blockIdx.x * 256 + threadIdx.x) * 4;
    if (i < n) {
        float4 v = *reinterpret_cast<const float4*>(in + i);
        ushort4 o;
        o.x = f2b(v.x); o.y = f2b(v.y); o.z = f2b(v.z); o.w = f2b(v.w);
        *reinterpret_cast<ushort4*>(out + i) = o;
    }
}

// ---------------------------------------------------------------------------
// 256x256 bf16 MFMA NT-GEMM (R5 proven structure: T2 swizzle + double buffer +
// per-quadrant phases + setprio). C[m][n] = sum_k A[m][k]*B[n][k].
// 512 thr = 8 waves (2Mx4N); per-wave 128x64 out; BK=64; LDS 128 KiB.
// NCOLS = logical N (also ldc); tail tile (NTB*256 > NCOLS) clamps B rows and
// guards C writes. Requires M%256==0, K%64==0, grid%8==0.
// ---------------------------------------------------------------------------
template<int NTB, int K, bool OBF16, int NCOLS>
__global__ __launch_bounds__(512, 2) void gemm256(const bf16_t* __restrict__ A,
                                                  const bf16_t* __restrict__ B,
                                                  void* __restrict__ Cv)
{
    constexpr int BK = 64;
    constexpr int NT = K / BK;
    constexpr bool HASTAIL = (NTB * 256 > NCOLS);
    const long ldc = NCOLS;
    __shared__ bf16_t As[2][256 * BK];
    __shared__ bf16_t Bs[2][256 * BK];

    const int nwg = gridDim.x;
    const int bid = blockIdx.x;
    const int wg  = ((nwg & 7) == 0) ? ((bid & 7) * (nwg >> 3) + (bid >> 3)) : bid;
    const int bm = (wg / NTB) * 256;
    const int bn = (wg % NTB) * 256;

    const int tid  = threadIdx.x;
    const int lane = tid & 63;
    const int wv   = tid >> 6;
    const int wr   = wv >> 2, wc = wv & 3;       // 2x4 wave grid
    const int l15  = lane & 15, l4 = lane >> 4;

    f32x4 acc[8][4];
    #pragma unroll
    for (int i = 0; i < 8; ++i)
        #pragma unroll
        for (int j = 0; j < 4; ++j) acc[i][j] = (f32x4){0.f, 0.f, 0.f, 0.f};

    const bf16_t* Abase = A + (long)bm * K;

    // stage K-tile t into buffer buf: linear LDS dest, inverse-swizzled global src
    auto stage = [&](int t, int buf) {
        const bf16_t* Ab = Abase + t * BK;
        #pragma unroll
        for (int it = 0; it < 4; ++it) {
            const int seg = it * 512 + tid;
            const int row = seg >> 3, c16 = seg & 7;
            const int sc = (c16 ^ (row & 7)) * 8;
            gload_lds16(Ab + (long)row * K + sc, &As[buf][seg * 8]);
            int br = bn + row;
            if (HASTAIL) br = min(br, NCOLS - 1);
            gload_lds16(B + (long)br * K + t * BK + sc, &Bs[buf][seg * 8]);
        }
    };

    stage(0, 0);
    asm volatile("s_waitcnt vmcnt(0)" ::: "memory");
    __builtin_amdgcn_s_barrier();

    for (int t = 0; t < NT; ++t) {
        const int cur = t & 1;
        if (t + 1 < NT) stage(t + 1, cur ^ 1);   // front-loaded prefetch, other buffer
        bf16x8 bfr[4], af[4];
        #pragma unroll
        for (int ks = 0; ks < 2; ++ks) {
            #pragma unroll
            for (int ni = 0; ni < 4; ++ni) {
                const int row = wc * 64 + ni * 16 + l15;
                const int ch = (ks * 4 + l4) ^ (row & 7);
                bfr[ni] = *reinterpret_cast<const bf16x8*>(&Bs[cur][row * 64 + ch * 8]);
            }
            #pragma unroll
            for (int qm = 0; qm < 2; ++qm) {
                #pragma unroll
                for (int mi = 0; mi < 4; ++mi) {
                    const int row = wr * 128 + qm * 64 + mi * 16 + l15;
                    const int ch = (ks * 4 + l4) ^ (row & 7);
                    af[mi] = *reinterpret_cast<const bf16x8*>(&As[cur][row * 64 + ch * 8]);
                }
                __builtin_amdgcn_s_setprio(1);
                #pragma unroll
                for (int mi = 0; mi < 4; ++mi)
                    #pragma unroll
                    for (int ni = 0; ni < 4; ++ni)
                        acc[qm * 4 + mi][ni] = __builtin_amdgcn_mfma_f32_16x16x32_bf16(
                            af[mi], bfr[ni], acc[qm * 4 + mi][ni], 0, 0, 0);
                __builtin_amdgcn_s_setprio(0);
                if (ks * 2 + qm < 3) __builtin_amdgcn_s_barrier();   // phase cohesion
            }
        }
        asm volatile("s_waitcnt vmcnt(0)" ::: "memory");   // next tile staged
        __builtin_amdgcn_s_barrier();
    }

    #pragma unroll
    for (int mf = 0; mf < 8; ++mf) {
        const long grow0 = bm + wr * 128 + mf * 16 + l4 * 4;
        #pragma unroll
        for (int ni = 0; ni < 4; ++ni) {
            const int gcol = bn + wc * 64 + ni * 16 + l15;
            if (HASTAIL && gcol >= NCOLS) continue;
            #pragma unroll
            for (int j = 0; j < 4; ++j) {
                if (OBF16)
                    ((bf16_t*)Cv)[(grow0 + j) * ldc + gcol] = f2b(acc[mf][ni][j]);
                else
                    ((float*)Cv)[(grow0 + j) * ldc + gcol] = acc[mf][ni][j];
            }
        }
    }
}

// ---------------------------------------------------------------------------
// Fused causal depthwise conv (K=4), 4 consecutive columns, reading bf16 xBCzA.
// ---------------------------------------------------------------------------
__device__ __forceinline__ float4 conv4v(const bf16_t* __restrict__ xb, long m, int l,
                                         int col, const float* __restrict__ cw,
                                         const float* __restrict__ cbv)
{
    float4 acc = *reinterpret_cast<const float4*>(cbv + col);
    float4 wc0 = *reinterpret_cast<const float4*>(cw + (long)col * 4);
    float4 wc1 = *reinterpret_cast<const float4*>(cw + (long)col * 4 + 4);
    float4 wc2 = *reinterpret_cast<const float4*>(cw + (long)col * 4 + 8);
    float4 wc3 = *reinterpret_cast<const float4*>(cw + (long)col * 4 + 12);
    const float t0[4] = {wc0.x, wc0.y, wc0.z, wc0.w};
    const float t1[4] = {wc1.x, wc1.y, wc1.z, wc1.w};
    const float t2[4] = {wc2.x, wc2.y, wc2.z, wc2.w};
    const float t3[4] = {wc3.x, wc3.y, wc3.z, wc3.w};
    #pragma unroll
    for (int tap = 0; tap < 4; ++tap) {
        if (l - 3 + tap < 0) continue;
        const bf16_t* p = xb + (m - 3 + tap) * (long)IN_OUT + col;
        ushort4 v = *reinterpret_cast<const ushort4*>(p);
        acc.x = fmaf(b2f(v.x), t0[tap], acc.x);
        acc.y = fmaf(b2f(v.y), t1[tap], acc.y);
        acc.z = fmaf(b2f(v.z), t2[tap], acc.z);
        acc.w = fmaf(b2f(v.w), t3[tap], acc.w);
    }
    return acc;
}

// ---------------------------------------------------------------------------
// Phase A (MFMA): per (b, chunk, head):
//   dt = softplus(A_log) (self-computed), cum = parallel inclusive scan(-dt),
//   states[p][n] = sum_k x[k][p] * (B[k][n]*exp(clast-cum[k]))  via
//   xT (64x128) MFMA BT_scaled (64x128). Writes states f32, cumbuf, cdecay.
// ---------------------------------------------------------------------------
__global__ __launch_bounds__(256) void ssd_states(const bf16_t* __restrict__ xb,
                                                  const float* __restrict__ cw,
                                                  const float* __restrict__ cbv,
                                                  float* __restrict__ states,
                                                  float* __restrict__ cumbuf,
                                                  float* __restrict__ cdecay)
{
    const int h = blockIdx.x, c = blockIdx.y, b = blockIdx.z;
    __shared__ bf16_t sx [128 * 64];   // x  row-major swizzled
    __shared__ bf16_t sBr[128 * 64];   // B  row-major swizzled
    __shared__ bf16_t sXT[64 * 128];   // x^T
    __shared__ bf16_t sBT[64 * 128];   // (B*decay)^T
    __shared__ float  cum[CHUNK];
    const int t = threadIdx.x;
    const long mbase = (long)b * SEQ + (long)c * CHUNK;
    const long cb = ((long)b * NCHUNK + c) * N_QK + h;

    // softplus(A_log) -> cum seed
    if (t < CHUNK) {
        const float a = b2f(xb[(mbase + t) * (long)IN_OUT + (CONV_DIM + D_INNER) + h]);
        cum[t] = -((a > 20.f) ? a : log1pf(expf(a)));
    }
    // stage x, B with fused conv
    for (int idx = t; idx < CHUNK * 16; idx += 256) {
        const int k = idx >> 4, q4 = (idx & 15) * 4;
        const long m = mbase + k;
        const int l = (int)(m & (SEQ - 1));
        float4 xv = conv4v(xb, m, l, h * 64 + q4, cw, cbv);
        float4 bv = conv4v(xb, m, l, D_INNER + h * 64 + q4, cw, cbv);
        store4b(&sx [SWZ64(k, q4)], xv);
        store4b(&sBr[SWZ64(k, q4)], bv);
    }
    __syncthreads();
    // Hillis-Steele inclusive scan over 128 elems
    #pragma unroll
    for (int s = 1; s < CHUNK; s <<= 1) {
        float pv = 0.f;
        if (t < CHUNK && t >= s) pv = cum[t - s];
        __syncthreads();
        if (t < CHUNK && t >= s) cum[t] += pv;
        __syncthreads();
    }
    const float clast = cum[CHUNK - 1];
    // transpose x -> sXT; B*decay -> sBT
    {
        const int j = t & 127;
        const int c8b = (t >> 7) * 4;
        const float ej = __expf(clast - cum[j]);
        #pragma unroll
        for (int it = 0; it < 4; ++it) {
            const int c8 = c8b + it;
            bf16x8 xv = *reinterpret_cast<const bf16x8*>(&sx [SWZ64(j, c8 * 8)]);
            bf16x8 bv = *reinterpret_cast<const bf16x8*>(&sBr[SWZ64(j, c8 * 8)]);
            #pragma unroll
            for (int e = 0; e < 8; ++e) {
                sXT[SWZ128(c8 * 8 + e, j)] = xv[e];
                sBT[SWZ128(c8 * 8 + e, j)] = f2b(b2f((bf16_t)bv[e]) * ej);
            }
        }
    }
    __syncthreads();

    // MFMA: wave w owns p-rows [w*16, w*16+16); D[p][n], K=128
    const int lane = t & 63, wv = t >> 6;
    const int l15 = lane & 15, l4 = lane >> 4;
    f32x4 acc[4];
    #pragma unroll
    for (int nj = 0; nj < 4; ++nj) acc[nj] = (f32x4){0.f, 0.f, 0.f, 0.f};
    #pragma unroll
    for (int ks = 0; ks < 4; ++ks) {
        const int kc = ks * 32 + l4 * 8;
        bf16x8 af = *reinterpret_cast<const bf16x8*>(&sXT[SWZ128(wv * 16 + l15, kc)]);
        #pragma unroll
        for (int nj = 0; nj < 4; ++nj) {
            bf16x8 bf = *reinterpret_cast<const bf16x8*>(&sBT[SWZ128(nj * 16 + l15, kc)]);
            acc[nj] = __builtin_amdgcn_mfma_f32_16x16x32_bf16(af, bf, acc[nj], 0, 0, 0);
        }
    }
    // C-write: row p = wv*16 + l4*4 + jj, col n = nj*16 + l15
    #pragma unroll
    for (int nj = 0; nj < 4; ++nj) {
        #pragma unroll
        for (int jj = 0; jj < 4; ++jj) {
            const int p = wv * 16 + l4 * 4 + jj;
            states[cb * 4096 + (long)p * 64 + nj * 16 + l15] = acc[nj][jj];
        }
    }
    if (t < CHUNK) cumbuf[cb * CHUNK + t] = cum[t];
    if (t == 0)   cdecay[cb] = __expf(clast);
}

// ---------------------------------------------------------------------------
// Phase B: sequential inter-chunk scan. 256 blocks = (b,h) x 4 quarters.
// ---------------------------------------------------------------------------
__global__ __launch_bounds__(256) void ssd_scan(float* __restrict__ states,
                                                const float* __restrict__ cdecay)
{
    const int bid = blockIdx.x;
    const int bh = bid >> 2, q = bid & 3;
    const int b = bh >> 5, h = bh & 31;
    const int t = threadIdx.x;
    const int off = q * 1024 + t * 4;
    float4 carry = make_float4(0.f, 0.f, 0.f, 0.f);
    for (int c = 0; c < NCHUNK; ++c) {
        const long cb = ((long)b * NCHUNK + c) * N_QK + h;
        const long base = cb * 4096 + off;
        const float cd = cdecay[cb];
        float4 st = *reinterpret_cast<const float4*>(&states[base]);
        *reinterpret_cast<float4*>(&states[base]) = carry;
        carry.x = fmaf(carry.x, cd, st.x);
        carry.y = fmaf(carry.y, cd, st.y);
        carry.z = fmaf(carry.z, cd, st.z);
        carry.w = fmaf(carry.w, cd, st.w);
    }
}

// ---------------------------------------------------------------------------
// Phase C (MFMA): S=C·B^T (tri+decay) -> Q bf16 -> y = Q·x + e·(C·prev^T) + D·x
// gate silu(z+zb) -> yz bf16. 4 waves, wave-private Q, no inner barriers.
// ---------------------------------------------------------------------------
__global__ __launch_bounds__(256) void ssd_out(const bf16_t* __restrict__ xb,
                                               const float* __restrict__ cumbuf,
                                               const float* __restrict__ prevst,
                                               const float* __restrict__ Dvec,
                                               const float* __restrict__ zbias,
                                               const float* __restrict__ cw,
                                               const float* __restrict__ cbv,
                                               bf16_t* __restrict__ yz)
{
    const int h = blockIdx.x, c = blockIdx.y, b = blockIdx.z;
    __shared__ bf16_t sC[128 * 64];
    __shared__ bf16_t sB[128 * 64];
    __shared__ bf16_t sXQ[128 * 64];   // x tile, later aliased as Q
    __shared__ bf16_t sXT[64 * 128];   // x^T
    __shared__ bf16_t sP[64 * 64];     // prev state (bf16)
    __shared__ float  cum[CHUNK];
    const int t = threadIdx.x;
    const long mbase = (long)b * SEQ + (long)c * CHUNK;
    const long cb = ((long)b * NCHUNK + c) * N_QK + h;
    if (t < CHUNK) cum[t] = cumbuf[cb * CHUNK + t];
    for (int idx = t; idx < CHUNK * 16; idx += 256) {
        const int k = idx >> 4, q4 = (idx & 15) * 4;
        const long m = mbase + k;
        const int l = (int)(m & (SEQ - 1));
        float4 xv = conv4v(xb, m, l, h * 64 + q4, cw, cbv);
        float4 bv = conv4v(xb, m, l, D_INNER + h * 64 + q4, cw, cbv);
        float4 cv = conv4v(xb, m, l, 2 * D_INNER + h * 64 + q4, cw, cbv);
        store4b(&sXQ[SWZ64(k, q4)], xv);
        store4b(&sB [SWZ64(k, q4)], bv);
        store4b(&sC [SWZ64(k, q4)], cv);
    }
    for (int idx = t; idx < 64 * 16; idx += 256) {
        const int p = idx >> 4, q4 = (idx & 15) * 4;
        float4 v = *reinterpret_cast<const float4*>(prevst + cb * 4096 + p * 64 + q4);
        store4b(&sP[SWZ64(p, q4)], v);
    }
    __syncthreads();
    {
        const int j = t & 127;
        const int c8b = (t >> 7) * 4;
        #pragma unroll
        for (int it = 0; it < 4; ++it) {
            const int c8 = c8b + it;
            bf16x8 v = *reinterpret_cast<const bf16x8*>(&sXQ[SWZ64(j, c8 * 8)]);
            #pragma unroll
            for (int e = 0; e < 8; ++e) sXT[SWZ128(c8 * 8 + e, j)] = v[e];
        }
    }
    __syncthreads();   // sXQ now dead as x; becomes wave-private Q

    const int lane = t & 63, wv = t >> 6;
    const int w32 = wv * 32, l15 = lane & 15, l4 = lane >> 4;
    bf16_t* sQ = sXQ;

    f32x4 yac[2][4], iac[2][4];
    #pragma unroll
    for (int mi = 0; mi < 2; ++mi)
        #pragma unroll
        for (int np = 0; np < 4; ++np) {
            yac[mi][np] = (f32x4){0.f, 0.f, 0.f, 0.f};
            iac[mi][np] = (f32x4){0.f, 0.f, 0.f, 0.f};
        }

    #pragma unroll
    for (int H = 0; H < 2; ++H) {
        if (H == 1 && wv < 2) break;
        const int j0 = H * 64;
        f32x4 sac[2][4];
        #pragma unroll
        for (int mi = 0; mi < 2; ++mi)
            #pragma unroll
            for (int nj = 0; nj < 4; ++nj) sac[mi][nj] = (f32x4){0.f, 0.f, 0.f, 0.f};
        #pragma unroll
        for (int kk = 0; kk < 2; ++kk) {
            const int kc = kk * 32 + l4 * 8;
            bf16x8 af0 = *reinterpret_cast<const bf16x8*>(&sC[SWZ64(w32 + l15, kc)]);
            bf16x8 af1 = *reinterpret_cast<const bf16x8*>(&sC[SWZ64(w32 + 16 + l15, kc)]);
            #pragma unroll
            for (int nj = 0; nj < 4; ++nj) {
                bf16x8 bfj = *reinterpret_cast<const bf16x8*>(&sB[SWZ64(j0 + nj * 16 + l15, kc)]);
                if (j0 + nj * 16 <= w32 + 15)
                    sac[0][nj] = __builtin_amdgcn_mfma_f32_16x16x32_bf16(af0, bfj, sac[0][nj], 0, 0, 0);
                if (j0 + nj * 16 <= w32 + 31)
                    sac[1][nj] = __builtin_amdgcn_mfma_f32_16x16x32_bf16(af1, bfj, sac[1][nj], 0, 0, 0);
            }
        }
        #pragma unroll
        for (int mi = 0; mi < 2; ++mi) {
            #pragma unroll
            for (int nj = 0; nj < 4; ++nj) {
                const int jcol = nj * 16 + l15;
                const int jg = j0 + jcol;
                #pragma unroll
                for (int jj = 0; jj < 4; ++jj) {
                    const int i = w32 + mi * 16 + l4 * 4 + jj;
                    const float q = (jg <= i) ? __expf(cum[i] - cum[jg]) * sac[mi][nj][jj] : 0.f;
                    sQ[SWZ64(i, jcol)] = f2b(q);
                }
            }
        }
        #pragma unroll
        for (int kk = 0; kk < 2; ++kk) {
            const int kc = kk * 32 + l4 * 8;
            bf16x8 qa0 = *reinterpret_cast<const bf16x8*>(&sQ[SWZ64(w32 + l15, kc)]);
            bf16x8 qa1 = *reinterpret_cast<const bf16x8*>(&sQ[SWZ64(w32 + 16 + l15, kc)]);
            #pragma unroll
            for (int np = 0; np < 4; ++np) {
                bf16x8 xf = *reinterpret_cast<const bf16x8*>(&sXT[SWZ128(np * 16 + l15, j0 + kc)]);
                yac[0][np] = __builtin_amdgcn_mfma_f32_16x16x32_bf16(qa0, xf, yac[0][np], 0, 0, 0);
                yac[1][np] = __builtin_amdgcn_mfma_f32_16x16x32_bf16(qa1, xf, yac[1][np], 0, 0, 0);
            }
        }
    }
    #pragma unroll
    for (int kk = 0; kk < 2; ++kk) {
        const int kc = kk * 32 + l4 * 8;
        bf16x8 cf0 = *reinterpret_cast<const bf16x8*>(&sC[SWZ64(w32 + l15, kc)]);
        bf16x8 cf1 = *reinterpret_cast<const bf16x8*>(&sC[SWZ64(w32 + 16 + l15, kc)]);
        #pragma unroll
        for (int np = 0; np < 4; ++np) {
            bf16x8 pf = *reinterpret_cast<const bf16x8*>(&sP[SWZ64(np * 16 + l15, kc)]);
            iac[0][np] = __builtin_amdgcn_mfma_f32_16x16x32_bf16(cf0, pf, iac[0][np], 0, 0, 0);
            iac[1][np] = __builtin_amdgcn_mfma_f32_16x16x32_bf16(cf1, pf, iac[1][np], 0, 0, 0);
        }
    }
    const float dh = Dvec[h];
    #pragma unroll
    for (int mi = 0; mi < 2; ++mi) {
        #pragma unroll
        for (int jj = 0; jj < 4; ++jj) {
            const int i = w32 + mi * 16 + l4 * 4 + jj;
            const float ei = __expf(cum[i]);
            const long m = mbase + i;
            const bf16_t* zr = xb + m * (long)IN_OUT + CONV_DIM + h * 64;
            bf16_t* orow = yz + m * (long)D_INNER + h * 64;
            #pragma unroll
            for (int np = 0; np < 4; ++np) {
                const int p = np * 16 + l15;
                const float xval = b2f(sXT[SWZ128(p, i)]);
                const float y = yac[mi][np][jj] + ei * iac[mi][np][jj] + dh * xval;
                const float zv = b2f(zr[p]) + zbias[h * 64 + p];
                const float s = zv / (1.f + __expf(-zv));
                orow[p] = f2b(y * s);
            }
        }
    }
}

// ---------------------------------------------------------------------------
extern "C" void kernel_launch(void* const* d_in, const int* in_sizes, int n_in,
                              void* d_out, int out_size, void* d_ws, size_t ws_size,
                              hipStream_t stream)
{
    const float* u      = (const float*)d_in[0];
    const float* W_in   = (const float*)d_in[1];
    const float* conv_w = (const float*)d_in[2];
    const float* conv_b = (const float*)d_in[3];
    const float* Dv     = (const float*)d_in[4];
    const float* z_bias = (const float*)d_in[5];
    const float* W_out  = (const float*)d_in[6];
    float* out = (float*)d_out;

    char* w = (char*)d_ws;
    bf16_t* xbcza = (bf16_t*)w;  w += (long)M_ROWS * IN_OUT * 2;   // 128.5 MiB
    bf16_t* wob   = (bf16_t*)w;  w += (long)2048 * 2048 * 2;       //   8 MiB
    char* ureg = w;                                                 // ~66 MiB union
    bf16_t* ub  = (bf16_t*)ureg;                                    // 32 MiB (phase 1)
    bf16_t* wib = (bf16_t*)(ureg + (long)M_ROWS * D_MODEL * 2);     // 32.125 MiB (phase 1)
    bf16_t* yzb = (bf16_t*)ureg;                                    // 32 MiB (phase 2)
    float*  cumb   = (float*)(ureg + (long)M_ROWS * D_INNER * 2);   //  1 MiB
    float*  states = cumb + (long)BATCH * NCHUNK * N_QK * CHUNK;    // 32 MiB
    float*  cdec   = states + (long)BATCH * NCHUNK * N_QK * 4096;   //  8 KiB

    f2b_kernel<<<(int)(((long)M_ROWS * D_MODEL / 4 + 255) / 256), 256, 0, stream>>>(
        u, ub, (long)M_ROWS * D_MODEL);
    f2b_kernel<<<(int)(((long)IN_OUT * D_MODEL / 4 + 255) / 256), 256, 0, stream>>>(
        W_in, wib, (long)IN_OUT * D_MODEL);
    f2b_kernel<<<(int)(((long)D_MODEL * D_INNER / 4 + 255) / 256), 256, 0, stream>>>(
        W_out, wob, (long)D_MODEL * D_INNER);

    // GEMM1: full 8224 cols (tail tile guarded), 32 x 33 = 1056 wgs
    gemm256<33, D_MODEL, true, IN_OUT><<<(M_ROWS / 256) * 33, 512, 0, stream>>>(
        ub, wib, xbcza);

    ssd_states<<<dim3(N_QK, NCHUNK, BATCH), 256, 0, stream>>>(xbcza, conv_w, conv_b,
                                                              states, cumb, cdec);

    ssd_scan<<<BATCH * N_QK * 4, 256, 0, stream>>>(states, cdec);

    ssd_out<<<dim3(N_QK, NCHUNK, BATCH), 256, 0, stream>>>(xbcza, cumb, states, Dv, z_bias,
                                                           conv_w, conv_b, yzb);

    // GEMM2: out = yz @ W_out^T  (8192 x 2048 x 2048), 32x8 = 256 wgs
    gemm256<8, D_INNER, false, D_MODEL><<<(M_ROWS / 256) * 8, 512, 0, stream>>>(
        yzb, wob, out);
}

// Round 9
// 830.632 us; speedup vs baseline: 1.1210x; 1.0088x over previous
//
#include <hip/hip_runtime.h>
#include <math.h>

#define D_MODEL  2048
#define D_INNER  2048
#define N_QK     32
#define N_V      32
#define D_STATE  64
#define D_CONV   4
#define CHUNK    128
#define CONV_DIM 6144      // D_INNER + 2*N_QK*D_STATE
#define IN_OUT   8224      // 2*D_INNER + 2*N_QK*D_STATE + N_V
#define BATCH    2
#define SEQ      4096
#define M_ROWS   (BATCH*SEQ)   // 8192
#define NCHUNK   (SEQ/CHUNK)   // 32

typedef unsigned short bf16_t;
typedef __attribute__((ext_vector_type(4))) float f32x4;
typedef __attribute__((ext_vector_type(8))) short bf16x8;

// swizzled row-major LDS index (elem units); XOR bits 3-5 spread rows over banks
#define SWZ64(r,c)  ((((r)*64)  + (c)) ^ (((r)&7)<<3))
#define SWZ128(r,c) ((((r)*128) + (c)) ^ (((r)&7)<<3))

__device__ __forceinline__ float b2f(bf16_t u) {
    union { unsigned int i; float f; } w; w.i = ((unsigned int)u) << 16; return w.f;
}
__device__ __forceinline__ bf16_t f2b(float f) {
    unsigned int x = __float_as_uint(f);
    return (bf16_t)((x + 0x7FFFu + ((x >> 16) & 1u)) >> 16);   // RNE
}
__device__ __forceinline__ void store4b(bf16_t* dst, float4 v) {
    ushort4 u; u.x = f2b(v.x); u.y = f2b(v.y); u.z = f2b(v.z); u.w = f2b(v.w);
    *reinterpret_cast<ushort4*>(dst) = u;
}

__device__ __forceinline__ void gload_lds16(const bf16_t* g, bf16_t* l) {
    __builtin_amdgcn_global_load_lds((const __attribute__((address_space(1))) void*)g,
                                     (__attribute__((address_space(3))) void*)l,
                                     16, 0, 0);
}

// ---------------------------------------------------------------------------
// fp32 -> bf16 convert
// ---------------------------------------------------------------------------
__global__ __launch_bounds__(256) void f2b_kernel(const float* __restrict__ in,
                                                  bf16_t* __restrict__ out, long n)
{
    const long i = ((long)blockIdx.x * 256 + threadIdx.x) * 4;
    if (i < n) {
        float4 v = *reinterpret_cast<const float4*>(in + i);
        ushort4 o;
        o.x = f2b(v.x); o.y = f2b(v.y); o.z = f2b(v.z); o.w = f2b(v.w);
        *reinterpret_cast<ushort4*>(out + i) = o;
    }
}

// ---------------------------------------------------------------------------
// 256x256 bf16 MFMA NT-GEMM with K-half counted-vmcnt pipeline (fixed per
// rule #21: LINEAR per-lane LDS dest, involution on the GLOBAL source).
// LDS layout: As[buf][kh][row*4 + jp] (16B slots); physical chunk
// jp = jl ^ ((row>>1)&3), jl = logical chunk within the 32-col K-half.
// Stage t+1's K-half0 before P1, K-half1 after P2. Waits: mid vmcnt(8)
// (K1(t) landed), end vmcnt(4) (K0(t+1) landed) -- never 0 in steady state.
// 512 thr = 8 waves (2Mx4N); BK=64; 128 KiB LDS. No N-tail support.
// ---------------------------------------------------------------------------
template<int NTB, int K, bool OBF16>
__global__ __launch_bounds__(512, 2) void gemm256(const bf16_t* __restrict__ A,
                                                  const bf16_t* __restrict__ B,
                                                  void* __restrict__ Cv,
                                                  long ldc)
{
    constexpr int BK = 64;
    constexpr int NT = K / BK;
    __shared__ bf16_t As[2][2][8192];   // [buf][kh][1024 slots * 8 elems]
    __shared__ bf16_t Bs[2][2][8192];

    const int nwg = gridDim.x;
    const int bid = blockIdx.x;
    const int wg  = ((nwg & 7) == 0) ? ((bid & 7) * (nwg >> 3) + (bid >> 3)) : bid;
    const int bm = (wg / NTB) * 256;
    const int bn = (wg % NTB) * 256;

    const int tid  = threadIdx.x;
    const int lane = tid & 63;
    const int wv   = tid >> 6;
    const int wr   = wv >> 2, wc = wv & 3;       // 2x4 wave grid
    const int l15  = lane & 15, l4 = lane >> 4;

    f32x4 acc[8][4];
    #pragma unroll
    for (int i = 0; i < 8; ++i)
        #pragma unroll
        for (int j = 0; j < 4; ++j) acc[i][j] = (f32x4){0.f, 0.f, 0.f, 0.f};

    const bf16_t* Abase = A + (long)bm * K;
    const bf16_t* Bbase = B + (long)bn * K;

    // stage one K-half of tile t into buffer buf. 4 loads/thread (2A+2B).
    // LDS dest slot s = row*4+jp is LINEAR in tid (uniform + lane*16B);
    // the involution jp <-> jl is applied to the GLOBAL source column.
    auto stage_half = [&](int t, int buf, int kh) {
        #pragma unroll
        for (int it = 0; it < 2; ++it) {
            const int s   = it * 512 + tid;          // 0..1023
            const int row = s >> 2;                  // 0..255
            const int jp  = s & 3;                   // physical chunk in half
            const int jl  = jp ^ ((row >> 1) & 3);   // logical chunk in half
            const long go = (long)row * K + t * BK + kh * 32 + jl * 8;
            gload_lds16(Abase + go, &As[buf][kh][s * 8]);
            gload_lds16(Bbase + go, &Bs[buf][kh][s * 8]);
        }
    };
    // read the 8-elem fragment for (row, logical chunk l4) of half kh
    auto rdA = [&](int buf, int kh, int row) {
        const int jp = l4 ^ ((row >> 1) & 3);
        return *reinterpret_cast<const bf16x8*>(&As[buf][kh][(row * 4 + jp) * 8]);
    };
    auto rdB = [&](int buf, int kh, int row) {
        const int jp = l4 ^ ((row >> 1) & 3);
        return *reinterpret_cast<const bf16x8*>(&Bs[buf][kh][(row * 4 + jp) * 8]);
    };

    stage_half(0, 0, 0);
    stage_half(0, 0, 1);
    asm volatile("s_waitcnt vmcnt(4)" ::: "memory");   // K-half0 of tile 0 landed
    __builtin_amdgcn_s_barrier();

    for (int t = 0; t < NT; ++t) {
        const int cur = t & 1;
        bf16x8 bfr[4], af[4];
        if (t + 1 < NT) stage_half(t + 1, cur ^ 1, 0);
        // P1: ks=0, qm=0
        #pragma unroll
        for (int ni = 0; ni < 4; ++ni) bfr[ni] = rdB(cur, 0, wc * 64 + ni * 16 + l15);
        #pragma unroll
        for (int mi = 0; mi < 4; ++mi) af[mi] = rdA(cur, 0, wr * 128 + mi * 16 + l15);
        __builtin_amdgcn_s_setprio(1);
        #pragma unroll
        for (int mi = 0; mi < 4; ++mi)
            #pragma unroll
            for (int ni = 0; ni < 4; ++ni)
                acc[mi][ni] = __builtin_amdgcn_mfma_f32_16x16x32_bf16(
                    af[mi], bfr[ni], acc[mi][ni], 0, 0, 0);
        __builtin_amdgcn_s_setprio(0);
        __builtin_amdgcn_s_barrier();
        // P2: ks=0, qm=1
        #pragma unroll
        for (int mi = 0; mi < 4; ++mi) af[mi] = rdA(cur, 0, wr * 128 + 64 + mi * 16 + l15);
        __builtin_amdgcn_s_setprio(1);
        #pragma unroll
        for (int mi = 0; mi < 4; ++mi)
            #pragma unroll
            for (int ni = 0; ni < 4; ++ni)
                acc[4 + mi][ni] = __builtin_amdgcn_mfma_f32_16x16x32_bf16(
                    af[mi], bfr[ni], acc[4 + mi][ni], 0, 0, 0);
        __builtin_amdgcn_s_setprio(0);
        // stage K-half1 of t+1, then guarantee K-half1 of t landed
        if (t + 1 < NT) {
            stage_half(t + 1, cur ^ 1, 1);
            asm volatile("s_waitcnt vmcnt(8)" ::: "memory");   // oldest 4 = K1(t)
        } else {
            asm volatile("s_waitcnt vmcnt(0)" ::: "memory");
        }
        __builtin_amdgcn_s_barrier();
        // P3: ks=1, qm=0
        #pragma unroll
        for (int ni = 0; ni < 4; ++ni) bfr[ni] = rdB(cur, 1, wc * 64 + ni * 16 + l15);
        #pragma unroll
        for (int mi = 0; mi < 4; ++mi) af[mi] = rdA(cur, 1, wr * 128 + mi * 16 + l15);
        __builtin_amdgcn_s_setprio(1);
        #pragma unroll
        for (int mi = 0; mi < 4; ++mi)
            #pragma unroll
            for (int ni = 0; ni < 4; ++ni)
                acc[mi][ni] = __builtin_amdgcn_mfma_f32_16x16x32_bf16(
                    af[mi], bfr[ni], acc[mi][ni], 0, 0, 0);
        __builtin_amdgcn_s_setprio(0);
        __builtin_amdgcn_s_barrier();
        // P4: ks=1, qm=1
        #pragma unroll
        for (int mi = 0; mi < 4; ++mi) af[mi] = rdA(cur, 1, wr * 128 + 64 + mi * 16 + l15);
        __builtin_amdgcn_s_setprio(1);
        #pragma unroll
        for (int mi = 0; mi < 4; ++mi)
            #pragma unroll
            for (int ni = 0; ni < 4; ++ni)
                acc[4 + mi][ni] = __builtin_amdgcn_mfma_f32_16x16x32_bf16(
                    af[mi], bfr[ni], acc[4 + mi][ni], 0, 0, 0);
        __builtin_amdgcn_s_setprio(0);
        // counted end wait: K0(t+1) landed, K1(t+1) stays in flight
        if (t + 1 < NT) { asm volatile("s_waitcnt vmcnt(4)" ::: "memory"); }
        __builtin_amdgcn_s_barrier();
    }

    #pragma unroll
    for (int mf = 0; mf < 8; ++mf) {
        const long grow0 = bm + wr * 128 + mf * 16 + l4 * 4;   // acc[mf] <-> row wr*128+mf*16
        #pragma unroll
        for (int ni = 0; ni < 4; ++ni) {
            const int gcol = bn + wc * 64 + ni * 16 + l15;
            #pragma unroll
            for (int j = 0; j < 4; ++j) {
                if (OBF16)
                    ((bf16_t*)Cv)[(grow0 + j) * ldc + gcol] = f2b(acc[mf][ni][j]);
                else
                    ((float*)Cv)[(grow0 + j) * ldc + gcol] = acc[mf][ni][j];
            }
        }
    }
}

// ---------------------------------------------------------------------------
// 128x128 m97-style MFMA GEMM (A_log 32-col tail), ldc-param.
// ---------------------------------------------------------------------------
template<int N, int K, bool OBF16>
__global__ __launch_bounds__(256) void gemm_mfma(const bf16_t* __restrict__ A,
                                                 const bf16_t* __restrict__ B,
                                                 void* __restrict__ Cv,
                                                 long ldc)
{
    constexpr int BM = 128, BN = 128, BK = 64;
    constexpr int NTB = (N + BN - 1) / BN;
    __shared__ bf16_t As[BM * BK];
    __shared__ bf16_t Bs[BM * BK];

    const int nwg = gridDim.x;
    const int bid = blockIdx.x;
    const int wg  = ((nwg & 7) == 0) ? ((bid & 7) * (nwg >> 3) + (bid >> 3)) : bid;
    const int bm = (wg / NTB) * BM;
    const int bn = (wg % NTB) * BN;

    const int tid  = threadIdx.x;
    const int lane = tid & 63;
    const int wv   = tid >> 6;
    const int wr   = wv >> 1, wc = wv & 1;

    f32x4 acc[4][4];
    #pragma unroll
    for (int i = 0; i < 4; ++i)
        #pragma unroll
        for (int j = 0; j < 4; ++j) acc[i][j] = (f32x4){0.f, 0.f, 0.f, 0.f};

    for (int k0 = 0; k0 < K; k0 += BK) {
        #pragma unroll
        for (int it = 0; it < 4; ++it) {
            const int seg = it * 256 + tid;
            const int row = seg >> 3, c16 = seg & 7;
            gload_lds16(A + (long)(bm + row) * K + k0 + c16 * 8,
                        &As[row * BK + c16 * 8]);
            int brow = bn + row;
            if constexpr (N % BN != 0) brow = min(brow, N - 1);
            gload_lds16(B + (long)brow * K + k0 + c16 * 8,
                        &Bs[row * BK + c16 * 8]);
        }
        __syncthreads();
        #pragma unroll
        for (int kk = 0; kk < 2; ++kk) {
            bf16x8 af[4], bfr[4];
            const int kc = kk * 32 + (lane >> 4) * 8;
            #pragma unroll
            for (int mi = 0; mi < 4; ++mi) {
                const int row = wr * 64 + mi * 16 + (lane & 15);
                af[mi] = *reinterpret_cast<const bf16x8*>(&As[row * BK + kc]);
            }
            #pragma unroll
            for (int ni = 0; ni < 4; ++ni) {
                const int row = wc * 64 + ni * 16 + (lane & 15);
                bfr[ni] = *reinterpret_cast<const bf16x8*>(&Bs[row * BK + kc]);
            }
            #pragma unroll
            for (int mi = 0; mi < 4; ++mi)
                #pragma unroll
                for (int ni = 0; ni < 4; ++ni)
                    acc[mi][ni] = __builtin_amdgcn_mfma_f32_16x16x32_bf16(
                        af[mi], bfr[ni], acc[mi][ni], 0, 0, 0);
        }
        __syncthreads();
    }

    #pragma unroll
    for (int mi = 0; mi < 4; ++mi) {
        const long row0 = bm + wr * 64 + mi * 16 + ((lane >> 4) << 2);
        #pragma unroll
        for (int ni = 0; ni < 4; ++ni) {
            const int col = bn + wc * 64 + ni * 16 + (lane & 15);
            if (N % BN != 0 && col >= N) continue;
            #pragma unroll
            for (int j = 0; j < 4; ++j) {
                if (OBF16)
                    ((bf16_t*)Cv)[(row0 + j) * ldc + col] = f2b(acc[mi][ni][j]);
                else
                    ((float*)Cv)[(row0 + j) * ldc + col] = acc[mi][ni][j];
            }
        }
    }
}

// ---------------------------------------------------------------------------
// Fused causal depthwise conv (K=4), 4 consecutive columns, reading bf16 xBCzA.
// ---------------------------------------------------------------------------
__device__ __forceinline__ float4 conv4v(const bf16_t* __restrict__ xb, long m, int l,
                                         int col, const float* __restrict__ cw,
                                         const float* __restrict__ cbv)
{
    float4 acc = *reinterpret_cast<const float4*>(cbv + col);
    float4 wc0 = *reinterpret_cast<const float4*>(cw + (long)col * 4);
    float4 wc1 = *reinterpret_cast<const float4*>(cw + (long)col * 4 + 4);
    float4 wc2 = *reinterpret_cast<const float4*>(cw + (long)col * 4 + 8);
    float4 wc3 = *reinterpret_cast<const float4*>(cw + (long)col * 4 + 12);
    const float t0[4] = {wc0.x, wc0.y, wc0.z, wc0.w};
    const float t1[4] = {wc1.x, wc1.y, wc1.z, wc1.w};
    const float t2[4] = {wc2.x, wc2.y, wc2.z, wc2.w};
    const float t3[4] = {wc3.x, wc3.y, wc3.z, wc3.w};
    #pragma unroll
    for (int tap = 0; tap < 4; ++tap) {
        if (l - 3 + tap < 0) continue;
        const bf16_t* p = xb + (m - 3 + tap) * (long)IN_OUT + col;
        ushort4 v = *reinterpret_cast<const ushort4*>(p);
        acc.x = fmaf(b2f(v.x), t0[tap], acc.x);
        acc.y = fmaf(b2f(v.y), t1[tap], acc.y);
        acc.z = fmaf(b2f(v.z), t2[tap], acc.z);
        acc.w = fmaf(b2f(v.w), t3[tap], acc.w);
    }
    return acc;
}

// ---------------------------------------------------------------------------
// Phase A (MFMA): dt=softplus (self), parallel cumsum, states via MFMA.
// ---------------------------------------------------------------------------
__global__ __launch_bounds__(256) void ssd_states(const bf16_t* __restrict__ xb,
                                                  const float* __restrict__ cw,
                                                  const float* __restrict__ cbv,
                                                  float* __restrict__ states,
                                                  float* __restrict__ cumbuf,
                                                  float* __restrict__ cdecay)
{
    const int h = blockIdx.x, c = blockIdx.y, b = blockIdx.z;
    __shared__ bf16_t sx [128 * 64];
    __shared__ bf16_t sBr[128 * 64];
    __shared__ bf16_t sXT[64 * 128];
    __shared__ bf16_t sBT[64 * 128];
    __shared__ float  cum[CHUNK];
    const int t = threadIdx.x;
    const long mbase = (long)b * SEQ + (long)c * CHUNK;
    const long cb = ((long)b * NCHUNK + c) * N_QK + h;

    if (t < CHUNK) {
        const float a = b2f(xb[(mbase + t) * (long)IN_OUT + (CONV_DIM + D_INNER) + h]);
        cum[t] = -((a > 20.f) ? a : log1pf(expf(a)));
    }
    for (int idx = t; idx < CHUNK * 16; idx += 256) {
        const int k = idx >> 4, q4 = (idx & 15) * 4;
        const long m = mbase + k;
        const int l = (int)(m & (SEQ - 1));
        float4 xv = conv4v(xb, m, l, h * 64 + q4, cw, cbv);
        float4 bv = conv4v(xb, m, l, D_INNER + h * 64 + q4, cw, cbv);
        store4b(&sx [SWZ64(k, q4)], xv);
        store4b(&sBr[SWZ64(k, q4)], bv);
    }
    __syncthreads();
    #pragma unroll
    for (int s = 1; s < CHUNK; s <<= 1) {
        float pv = 0.f;
        if (t < CHUNK && t >= s) pv = cum[t - s];
        __syncthreads();
        if (t < CHUNK && t >= s) cum[t] += pv;
        __syncthreads();
    }
    const float clast = cum[CHUNK - 1];
    {
        const int j = t & 127;
        const int c8b = (t >> 7) * 4;
        const float ej = __expf(clast - cum[j]);
        #pragma unroll
        for (int it = 0; it < 4; ++it) {
            const int c8 = c8b + it;
            bf16x8 xv = *reinterpret_cast<const bf16x8*>(&sx [SWZ64(j, c8 * 8)]);
            bf16x8 bv = *reinterpret_cast<const bf16x8*>(&sBr[SWZ64(j, c8 * 8)]);
            #pragma unroll
            for (int e = 0; e < 8; ++e) {
                sXT[SWZ128(c8 * 8 + e, j)] = xv[e];
                sBT[SWZ128(c8 * 8 + e, j)] = f2b(b2f((bf16_t)bv[e]) * ej);
            }
        }
    }
    __syncthreads();

    const int lane = t & 63, wv = t >> 6;
    const int l15 = lane & 15, l4 = lane >> 4;
    f32x4 acc[4];
    #pragma unroll
    for (int nj = 0; nj < 4; ++nj) acc[nj] = (f32x4){0.f, 0.f, 0.f, 0.f};
    #pragma unroll
    for (int ks = 0; ks < 4; ++ks) {
        const int kc = ks * 32 + l4 * 8;
        bf16x8 af = *reinterpret_cast<const bf16x8*>(&sXT[SWZ128(wv * 16 + l15, kc)]);
        #pragma unroll
        for (int nj = 0; nj < 4; ++nj) {
            bf16x8 bf = *reinterpret_cast<const bf16x8*>(&sBT[SWZ128(nj * 16 + l15, kc)]);
            acc[nj] = __builtin_amdgcn_mfma_f32_16x16x32_bf16(af, bf, acc[nj], 0, 0, 0);
        }
    }
    #pragma unroll
    for (int nj = 0; nj < 4; ++nj) {
        #pragma unroll
        for (int jj = 0; jj < 4; ++jj) {
            const int p = wv * 16 + l4 * 4 + jj;
            states[cb * 4096 + (long)p * 64 + nj * 16 + l15] = acc[nj][jj];
        }
    }
    if (t < CHUNK) cumbuf[cb * CHUNK + t] = cum[t];
    if (t == 0)   cdecay[cb] = __expf(clast);
}

// ---------------------------------------------------------------------------
// Phase B: sequential inter-chunk scan. 256 blocks = (b,h) x 4 quarters.
// ---------------------------------------------------------------------------
__global__ __launch_bounds__(256) void ssd_scan(float* __restrict__ states,
                                                const float* __restrict__ cdecay)
{
    const int bid = blockIdx.x;
    const int bh = bid >> 2, q = bid & 3;
    const int b = bh >> 5, h = bh & 31;
    const int t = threadIdx.x;
    const int off = q * 1024 + t * 4;
    float4 carry = make_float4(0.f, 0.f, 0.f, 0.f);
    for (int c = 0; c < NCHUNK; ++c) {
        const long cb = ((long)b * NCHUNK + c) * N_QK + h;
        const long base = cb * 4096 + off;
        const float cd = cdecay[cb];
        float4 st = *reinterpret_cast<const float4*>(&states[base]);
        *reinterpret_cast<float4*>(&states[base]) = carry;
        carry.x = fmaf(carry.x, cd, st.x);
        carry.y = fmaf(carry.y, cd, st.y);
        carry.z = fmaf(carry.z, cd, st.z);
        carry.w = fmaf(carry.w, cd, st.w);
    }
}

// ---------------------------------------------------------------------------
// Phase C (MFMA): S=C·B^T (tri+decay) -> Q bf16 -> y = Q·x + e·(C·prev^T) + D·x
// gate silu(z+zb) -> yz bf16. 4 waves, wave-private Q, no inner barriers.
// ---------------------------------------------------------------------------
__global__ __launch_bounds__(256) void ssd_out(const bf16_t* __restrict__ xb,
                                               const float* __restrict__ cumbuf,
                                               const float* __restrict__ prevst,
                                               const float* __restrict__ Dvec,
                                               const float* __restrict__ zbias,
                                               const float* __restrict__ cw,
                                               const float* __restrict__ cbv,
                                               bf16_t* __restrict__ yz)
{
    const int h = blockIdx.x, c = blockIdx.y, b = blockIdx.z;
    __shared__ bf16_t sC[128 * 64];
    __shared__ bf16_t sB[128 * 64];
    __shared__ bf16_t sXQ[128 * 64];   // x tile, later aliased as Q
    __shared__ bf16_t sXT[64 * 128];   // x^T
    __shared__ bf16_t sP[64 * 64];     // prev state (bf16)
    __shared__ float  cum[CHUNK];
    const int t = threadIdx.x;
    const long mbase = (long)b * SEQ + (long)c * CHUNK;
    const long cb = ((long)b * NCHUNK + c) * N_QK + h;
    if (t < CHUNK) cum[t] = cumbuf[cb * CHUNK + t];
    for (int idx = t; idx < CHUNK * 16; idx += 256) {
        const int k = idx >> 4, q4 = (idx & 15) * 4;
        const long m = mbase + k;
        const int l = (int)(m & (SEQ - 1));
        float4 xv = conv4v(xb, m, l, h * 64 + q4, cw, cbv);
        float4 bv = conv4v(xb, m, l, D_INNER + h * 64 + q4, cw, cbv);
        float4 cv = conv4v(xb, m, l, 2 * D_INNER + h * 64 + q4, cw, cbv);
        store4b(&sXQ[SWZ64(k, q4)], xv);
        store4b(&sB [SWZ64(k, q4)], bv);
        store4b(&sC [SWZ64(k, q4)], cv);
    }
    for (int idx = t; idx < 64 * 16; idx += 256) {
        const int p = idx >> 4, q4 = (idx & 15) * 4;
        float4 v = *reinterpret_cast<const float4*>(prevst + cb * 4096 + p * 64 + q4);
        store4b(&sP[SWZ64(p, q4)], v);
    }
    __syncthreads();
    {
        const int j = t & 127;
        const int c8b = (t >> 7) * 4;
        #pragma unroll
        for (int it = 0; it < 4; ++it) {
            const int c8 = c8b + it;
            bf16x8 v = *reinterpret_cast<const bf16x8*>(&sXQ[SWZ64(j, c8 * 8)]);
            #pragma unroll
            for (int e = 0; e < 8; ++e) sXT[SWZ128(c8 * 8 + e, j)] = v[e];
        }
    }
    __syncthreads();   // sXQ now dead as x; becomes wave-private Q

    const int lane = t & 63, wv = t >> 6;
    const int w32 = wv * 32, l15 = lane & 15, l4 = lane >> 4;
    bf16_t* sQ = sXQ;

    f32x4 yac[2][4], iac[2][4];
    #pragma unroll
    for (int mi = 0; mi < 2; ++mi)
        #pragma unroll
        for (int np = 0; np < 4; ++np) {
            yac[mi][np] = (f32x4){0.f, 0.f, 0.f, 0.f};
            iac[mi][np] = (f32x4){0.f, 0.f, 0.f, 0.f};
        }

    #pragma unroll
    for (int H = 0; H < 2; ++H) {
        if (H == 1 && wv < 2) break;
        const int j0 = H * 64;
        f32x4 sac[2][4];
        #pragma unroll
        for (int mi = 0; mi < 2; ++mi)
            #pragma unroll
            for (int nj = 0; nj < 4; ++nj) sac[mi][nj] = (f32x4){0.f, 0.f, 0.f, 0.f};
        #pragma unroll
        for (int kk = 0; kk < 2; ++kk) {
            const int kc = kk * 32 + l4 * 8;
            bf16x8 af0 = *reinterpret_cast<const bf16x8*>(&sC[SWZ64(w32 + l15, kc)]);
            bf16x8 af1 = *reinterpret_cast<const bf16x8*>(&sC[SWZ64(w32 + 16 + l15, kc)]);
            #pragma unroll
            for (int nj = 0; nj < 4; ++nj) {
                bf16x8 bfj = *reinterpret_cast<const bf16x8*>(&sB[SWZ64(j0 + nj * 16 + l15, kc)]);
                if (j0 + nj * 16 <= w32 + 15)
                    sac[0][nj] = __builtin_amdgcn_mfma_f32_16x16x32_bf16(af0, bfj, sac[0][nj], 0, 0, 0);
                if (j0 + nj * 16 <= w32 + 31)
                    sac[1][nj] = __builtin_amdgcn_mfma_f32_16x16x32_bf16(af1, bfj, sac[1][nj], 0, 0, 0);
            }
        }
        #pragma unroll
        for (int mi = 0; mi < 2; ++mi) {
            #pragma unroll
            for (int nj = 0; nj < 4; ++nj) {
                const int jcol = nj * 16 + l15;
                const int jg = j0 + jcol;
                #pragma unroll
                for (int jj = 0; jj < 4; ++jj) {
                    const int i = w32 + mi * 16 + l4 * 4 + jj;
                    const float q = (jg <= i) ? __expf(cum[i] - cum[jg]) * sac[mi][nj][jj] : 0.f;
                    sQ[SWZ64(i, jcol)] = f2b(q);
                }
            }
        }
        #pragma unroll
        for (int kk = 0; kk < 2; ++kk) {
            const int kc = kk * 32 + l4 * 8;
            bf16x8 qa0 = *reinterpret_cast<const bf16x8*>(&sQ[SWZ64(w32 + l15, kc)]);
            bf16x8 qa1 = *reinterpret_cast<const bf16x8*>(&sQ[SWZ64(w32 + 16 + l15, kc)]);
            #pragma unroll
            for (int np = 0; np < 4; ++np) {
                bf16x8 xf = *reinterpret_cast<const bf16x8*>(&sXT[SWZ128(np * 16 + l15, j0 + kc)]);
                yac[0][np] = __builtin_amdgcn_mfma_f32_16x16x32_bf16(qa0, xf, yac[0][np], 0, 0, 0);
                yac[1][np] = __builtin_amdgcn_mfma_f32_16x16x32_bf16(qa1, xf, yac[1][np], 0, 0, 0);
            }
        }
    }
    #pragma unroll
    for (int kk = 0; kk < 2; ++kk) {
        const int kc = kk * 32 + l4 * 8;
        bf16x8 cf0 = *reinterpret_cast<const bf16x8*>(&sC[SWZ64(w32 + l15, kc)]);
        bf16x8 cf1 = *reinterpret_cast<const bf16x8*>(&sC[SWZ64(w32 + 16 + l15, kc)]);
        #pragma unroll
        for (int np = 0; np < 4; ++np) {
            bf16x8 pf = *reinterpret_cast<const bf16x8*>(&sP[SWZ64(np * 16 + l15, kc)]);
            iac[0][np] = __builtin_amdgcn_mfma_f32_16x16x32_bf16(cf0, pf, iac[0][np], 0, 0, 0);
            iac[1][np] = __builtin_amdgcn_mfma_f32_16x16x32_bf16(cf1, pf, iac[1][np], 0, 0, 0);
        }
    }
    const float dh = Dvec[h];
    #pragma unroll
    for (int mi = 0; mi < 2; ++mi) {
        #pragma unroll
        for (int jj = 0; jj < 4; ++jj) {
            const int i = w32 + mi * 16 + l4 * 4 + jj;
            const float ei = __expf(cum[i]);
            const long m = mbase + i;
            const bf16_t* zr = xb + m * (long)IN_OUT + CONV_DIM + h * 64;
            bf16_t* orow = yz + m * (long)D_INNER + h * 64;
            #pragma unroll
            for (int np = 0; np < 4; ++np) {
                const int p = np * 16 + l15;
                const float xval = b2f(sXT[SWZ128(p, i)]);
                const float y = yac[mi][np][jj] + ei * iac[mi][np][jj] + dh * xval;
                const float zv = b2f(zr[p]) + zbias[h * 64 + p];
                const float s = zv / (1.f + __expf(-zv));
                orow[p] = f2b(y * s);
            }
        }
    }
}

// ---------------------------------------------------------------------------
extern "C" void kernel_launch(void* const* d_in, const int* in_sizes, int n_in,
                              void* d_out, int out_size, void* d_ws, size_t ws_size,
                              hipStream_t stream)
{
    const float* u      = (const float*)d_in[0];
    const float* W_in   = (const float*)d_in[1];
    const float* conv_w = (const float*)d_in[2];
    const float* conv_b = (const float*)d_in[3];
    const float* Dv     = (const float*)d_in[4];
    const float* z_bias = (const float*)d_in[5];
    const float* W_out  = (const float*)d_in[6];
    float* out = (float*)d_out;

    char* w = (char*)d_ws;
    bf16_t* xbcza = (bf16_t*)w;  w += (long)M_ROWS * IN_OUT * 2;   // 128.5 MiB
    bf16_t* wob   = (bf16_t*)w;  w += (long)2048 * 2048 * 2;       //   8 MiB
    char* ureg = w;                                                 // ~66 MiB union
    bf16_t* ub  = (bf16_t*)ureg;                                    // 32 MiB (phase 1)
    bf16_t* wib = (bf16_t*)(ureg + (long)M_ROWS * D_MODEL * 2);     // 32.125 MiB (phase 1)
    bf16_t* yzb = (bf16_t*)ureg;                                    // 32 MiB (phase 2)
    float*  cumb   = (float*)(ureg + (long)M_ROWS * D_INNER * 2);   //  1 MiB
    float*  states = cumb + (long)BATCH * NCHUNK * N_QK * CHUNK;    // 32 MiB
    float*  cdec   = states + (long)BATCH * NCHUNK * N_QK * 4096;   //  8 KiB

    f2b_kernel<<<(int)(((long)M_ROWS * D_MODEL / 4 + 255) / 256), 256, 0, stream>>>(
        u, ub, (long)M_ROWS * D_MODEL);
    f2b_kernel<<<(int)(((long)IN_OUT * D_MODEL / 4 + 255) / 256), 256, 0, stream>>>(
        W_in, wib, (long)IN_OUT * D_MODEL);
    f2b_kernel<<<(int)(((long)D_MODEL * D_INNER / 4 + 255) / 256), 256, 0, stream>>>(
        W_out, wob, (long)D_MODEL * D_INNER);

    // GEMM1 main: cols [0, 8192), 32x32 = 1024 wgs
    gemm256<32, D_MODEL, true><<<(M_ROWS / 256) * 32, 512, 0, stream>>>(
        ub, wib, xbcza, IN_OUT);
    // GEMM1 tail: cols [8192, 8224) (A_log), 128^2 kernel, ldc = IN_OUT
    gemm_mfma<32, D_MODEL, true><<<(M_ROWS / 128), 256, 0, stream>>>(
        ub, wib + (long)8192 * D_MODEL, xbcza + 8192, IN_OUT);

    ssd_states<<<dim3(N_QK, NCHUNK, BATCH), 256, 0, stream>>>(xbcza, conv_w, conv_b,
                                                              states, cumb, cdec);

    ssd_scan<<<BATCH * N_QK * 4, 256, 0, stream>>>(states, cdec);

    ssd_out<<<dim3(N_QK, NCHUNK, BATCH), 256, 0, stream>>>(xbcza, cumb, states, Dv, z_bias,
                                                           conv_w, conv_b, yzb);

    // GEMM2: out = yz @ W_out^T  (8192 x 2048 x 2048), 32x8 = 256 wgs
    gemm256<8, D_INNER, false><<<(M_ROWS / 256) * 8, 512, 0, stream>>>(
        yzb, wob, out, D_MODEL);
}